// Round 1
// baseline (155.807 us; speedup 1.0000x reference)
//
#include <hip/hip_runtime.h>
#include <hip/hip_bf16.h>
#include <stdint.h>

#define B_ 256
#define D_ 10
#define P_ 1152
#define I_ 16
#define J_ 8

__device__ inline uint32_t pack_bf16(float a, float b) {
    uint32_t ua = __float_as_uint(a);
    uint32_t ub = __float_as_uint(b);
    // round-to-nearest-even bf16 truncation
    ua = (ua + 0x7fffu + ((ua >> 16) & 1u)) >> 16;
    ub = (ub + 0x7fffu + ((ub >> 16) & 1u)) >> 16;
    return ua | (ub << 16);
}

// Block per (b,d), d-major block order (consecutive blocks share d -> W[d] L2-hot).
// Computes u_hat[b,d,:,:] (bf16 packed), s0 = 0.1*sum_p u_hat, and n2[0] partial.
__global__ __launch_bounds__(256) void k_uhat(
    const float* __restrict__ x, const float* __restrict__ W,
    uint32_t* __restrict__ uhat, float* __restrict__ s, float* __restrict__ n2)
{
    const int bid = blockIdx.x;
    const int d = bid >> 8;      // grid = D_*B_ with d-major
    const int b = bid & 255;
    const int tid = threadIdx.x;

    __shared__ float xs[P_ * J_];      // 36,864 B: x[b,:,:]
    __shared__ float sp[4][16];

    const float4* xg = (const float4*)(x + (size_t)b * P_ * J_);
    float4* xls = (float4*)xs;
    #pragma unroll
    for (int idx = tid; idx < P_ * J_ / 4; idx += 256) xls[idx] = xg[idx];
    __syncthreads();

    const int team = tid >> 3;   // 0..31, one p at a time
    const int tl = tid & 7;      // lane handles i = 2*tl, 2*tl+1
    float sa0 = 0.f, sa1 = 0.f;

    for (int k = 0; k < P_ / 32; ++k) {
        const int p = team + k * 32;
        const float* xp = xs + p * J_;
        const float x0 = xp[0], x1 = xp[1], x2 = xp[2], x3 = xp[3];
        const float x4 = xp[4], x5 = xp[5], x6 = xp[6], x7 = xp[7];
        const float4* wp = (const float4*)(W + ((size_t)(d * P_ + p) * I_ + 2 * tl) * J_);
        const float4 wa = wp[0], wb = wp[1], wc = wp[2], wd = wp[3];
        float u0 = wa.x*x0 + wa.y*x1 + wa.z*x2 + wa.w*x3
                 + wb.x*x4 + wb.y*x5 + wb.z*x6 + wb.w*x7;
        float u1 = wc.x*x0 + wc.y*x1 + wc.z*x2 + wc.w*x3
                 + wd.x*x4 + wd.y*x5 + wd.z*x6 + wd.w*x7;
        sa0 += u0; sa1 += u1;
        uhat[((size_t)(b * D_ + d) * P_ + p) * 8 + tl] = pack_bf16(u0, u1);
    }

    // reduce over the 8 teams in each wave (lanes with equal tl)
    #pragma unroll
    for (int st = 8; st < 64; st <<= 1) {
        sa0 += __shfl_xor(sa0, st);
        sa1 += __shfl_xor(sa1, st);
    }
    const int wave = tid >> 6, lane = tid & 63;
    if (lane < 8) { sp[wave][2 * tl] = sa0; sp[wave][2 * tl + 1] = sa1; }
    __syncthreads();

    if (wave == 0) {
        float v = 0.f, v2 = 0.f;
        if (lane < 16) {
            v = 0.1f * (sp[0][lane] + sp[1][lane] + sp[2][lane] + sp[3][lane]);
            s[(size_t)(b * D_ + d) * I_ + lane] = v;
            v2 = v * v;
        }
        #pragma unroll
        for (int st = 1; st < 64; st <<= 1) v2 += __shfl_xor(v2, st);
        if (lane == 0) atomicAdd(n2, v2);
    }
}

// Block per b. Reads u_hat once; logits beta = u_hat . t (t = sum_r g_r*s_r),
// softmax over d, accumulates s_r, n2 partial.
__global__ __launch_bounds__(1024) void k_route(
    const uint32_t* __restrict__ uhat, const float* __restrict__ t,
    float* __restrict__ s, float* __restrict__ n2)
{
    const int b = blockIdx.x;
    const int tid = threadIdx.x;

    __shared__ float tls[D_ * I_];
    __shared__ float sw[16][D_ * I_];
    __shared__ float n2l;

    if (tid < D_ * I_) tls[tid] = t[(size_t)b * D_ * I_ + tid];
    if (tid == 0) n2l = 0.f;
    __syncthreads();

    const int team = tid >> 3;   // 0..127
    const int tl = tid & 7;      // i-pair (2tl, 2tl+1)
    float sacc[D_][2];
    #pragma unroll
    for (int d = 0; d < D_; ++d) { sacc[d][0] = 0.f; sacc[d][1] = 0.f; }

    for (int k = 0; k < 9; ++k) {
        const int p = team + k * 128;
        const uint32_t* up = uhat + ((size_t)b * D_ * P_ + p) * 8 + tl;
        float u[D_][2];
        float beta[D_];
        #pragma unroll
        for (int d = 0; d < D_; ++d) {
            const uint32_t w = up[(size_t)d * P_ * 8];
            const float u0 = __uint_as_float(w << 16);
            const float u1 = __uint_as_float(w & 0xffff0000u);
            u[d][0] = u0; u[d][1] = u1;
            float bp = u0 * tls[d * I_ + 2 * tl] + u1 * tls[d * I_ + 2 * tl + 1];
            bp += __shfl_xor(bp, 1);
            bp += __shfl_xor(bp, 2);
            bp += __shfl_xor(bp, 4);
            beta[d] = bp;
        }
        float m = beta[0];
        #pragma unroll
        for (int d = 1; d < D_; ++d) m = fmaxf(m, beta[d]);
        float c[D_]; float Z = 0.f;
        #pragma unroll
        for (int d = 0; d < D_; ++d) { c[d] = __expf(beta[d] - m); Z += c[d]; }
        const float rz = 1.f / Z;
        #pragma unroll
        for (int d = 0; d < D_; ++d) {
            const float cd = c[d] * rz;
            sacc[d][0] += cd * u[d][0];
            sacc[d][1] += cd * u[d][1];
        }
    }

    // reduce over 8 teams within each wave
    #pragma unroll
    for (int st = 8; st < 64; st <<= 1) {
        #pragma unroll
        for (int d = 0; d < D_; ++d) {
            sacc[d][0] += __shfl_xor(sacc[d][0], st);
            sacc[d][1] += __shfl_xor(sacc[d][1], st);
        }
    }
    const int wave = tid >> 6, lane = tid & 63;
    if (lane < 8) {
        #pragma unroll
        for (int d = 0; d < D_; ++d) {
            sw[wave][d * I_ + 2 * tl]     = sacc[d][0];
            sw[wave][d * I_ + 2 * tl + 1] = sacc[d][1];
        }
    }
    __syncthreads();

    if (tid < D_ * I_) {
        float v = 0.f;
        #pragma unroll
        for (int w2 = 0; w2 < 16; ++w2) v += sw[w2][tid];
        s[(size_t)b * D_ * I_ + tid] = v;
        atomicAdd(&n2l, v * v);
    }
    __syncthreads();
    if (tid == 0) atomicAdd(n2, n2l);
}

// g = (n2/(n2+1))/(sqrt(n2)+eps); mode 0: t = g*s; mode 1: t += g*s; mode 2: out = g*s
__global__ void k_squash(const float* __restrict__ s, float* __restrict__ t,
                         float* __restrict__ out, const float* __restrict__ n2p, int mode)
{
    const int i = blockIdx.x * 256 + threadIdx.x;
    const float n2 = *n2p;
    const float g = (n2 / (n2 + 1.f)) / (sqrtf(n2) + 1e-7f);
    const float v = g * s[i];
    if (mode == 0)      t[i] = v;
    else if (mode == 1) t[i] += v;
    else                out[i] = v;
}

extern "C" void kernel_launch(void* const* d_in, const int* in_sizes, int n_in,
                              void* d_out, int out_size, void* d_ws, size_t ws_size,
                              hipStream_t stream)
{
    const float* x = (const float*)d_in[0];   // [256,1152,8]
    const float* W = (const float*)d_in[1];   // [10,1152,16,8]
    float* out = (float*)d_out;               // [256,10,16]

    char* ws = (char*)d_ws;
    uint32_t* uhat = (uint32_t*)ws;                              // bf16x2, 94,371,840 B
    const size_t uhat_bytes = (size_t)B_ * D_ * P_ * I_ * 2;
    float* s  = (float*)(ws + uhat_bytes);                       // [B,D,16]
    float* t  = s + B_ * D_ * I_;                                // [B,D,16]
    float* n2 = t + B_ * D_ * I_;                                // [3]

    hipMemsetAsync(n2, 0, 3 * sizeof(float), stream);

    // r = 0 (c uniform = 0.1) fused with u_hat production
    k_uhat<<<B_ * D_, 256, 0, stream>>>(x, W, uhat, s, n2 + 0);
    k_squash<<<(B_ * D_ * I_) / 256, 256, 0, stream>>>(s, t, out, n2 + 0, 0);
    // r = 1
    k_route<<<B_, 1024, 0, stream>>>(uhat, t, s, n2 + 1);
    k_squash<<<(B_ * D_ * I_) / 256, 256, 0, stream>>>(s, t, out, n2 + 1, 1);
    // r = 2
    k_route<<<B_, 1024, 0, stream>>>(uhat, t, s, n2 + 2);
    k_squash<<<(B_ * D_ * I_) / 256, 256, 0, stream>>>(s, t, out, n2 + 2, 2);
}

// Round 2
// 117.925 us; speedup vs baseline: 1.3212x; 1.3212x over previous
//
#include <hip/hip_runtime.h>
#include <hip/hip_bf16.h>
#include <stdint.h>

#define B_ 256
#define D_ 10
#define P_ 1152
#define I_ 16
#define J_ 8

#define TP 48        // p-tile per block
#define NPT 24       // P_/TP
#define NBC 4        // b-chunks
#define BCH 64       // B_/NBC

__device__ inline uint32_t pack_bf16(float a, float b) {
    uint32_t ua = __float_as_uint(a);
    uint32_t ub = __float_as_uint(b);
    // round-to-nearest-even bf16 truncation
    ua = (ua + 0x7fffu + ((ua >> 16) & 1u)) >> 16;
    ub = (ub + 0x7fffu + ((ub >> 16) & 1u)) >> 16;
    return ua | (ub << 16);
}

// Block = (d, p-tile of 48, b-chunk of 64). W fragment lives in registers for
// the whole kernel; x streams through a double-buffered swizzled LDS tile.
// bid = (pt%8) + 8*((pt/8)*40 + d*4 + bc): all blocks touching a given p-tile
// land on one XCD -> W-slice + x-slice stay L2-resident per XCD.
__global__ __launch_bounds__(384) void k_uhat(
    const float* __restrict__ x, const float* __restrict__ W,
    uint32_t* __restrict__ uhat, float* __restrict__ s_part)
{
    const int bid = blockIdx.x;
    const int g = bid & 7;
    const int inner = bid >> 3;
    const int ptl = inner / 40;
    const int rem = inner - ptl * 40;
    const int d = rem >> 2;
    const int bc = rem & 3;
    const int pt = ptl * 8 + g;

    const int tid = threadIdx.x;
    const int team = tid >> 3;   // 0..47 -> one p
    const int tl = tid & 7;      // i-pair (2tl, 2tl+1)
    const int wave = tid >> 6;   // 0..5
    const int lane = tid & 63;
    const int p = pt * TP + team;

    __shared__ float xs[2][TP * J_];     // 2 x 1536 B
    __shared__ float sred[2][6][16];

    // W fragment -> registers (64 B/lane, once)
    const float4* wp = (const float4*)(W + ((size_t)(d * P_ + p) * I_ + 2 * tl) * J_);
    const float4 wa = wp[0], wb = wp[1], wc = wp[2], wd = wp[3];

    const int b0 = bc * BCH;
    const float* xg = x + (size_t)b0 * (P_ * J_) + pt * (TP * J_);
    // XOR-quad swizzle: element (p_local, j) stored at word 8*p_local + (j ^ 4*(p_local&1))
    const int swz = tid ^ ((tid & 8) >> 1);
    const int sel = (team & 1) << 2;

    xs[0][swz] = xg[tid];
    __syncthreads();

    for (int k = 0; k < BCH; ++k) {
        const int kb = k & 1;
        if (k + 1 < BCH) xs[kb ^ 1][swz] = xg[(size_t)(k + 1) * (P_ * J_) + tid];

        const float* xt = &xs[kb][team * J_];
        const float4 xA = *(const float4*)(xt + sel);         // x0..x3
        const float4 xB = *(const float4*)(xt + (sel ^ 4));   // x4..x7
        float u0 = wa.x*xA.x + wa.y*xA.y + wa.z*xA.z + wa.w*xA.w
                 + wb.x*xB.x + wb.y*xB.y + wb.z*xB.z + wb.w*xB.w;
        float u1 = wc.x*xA.x + wc.y*xA.y + wc.z*xA.z + wc.w*xA.w
                 + wd.x*xB.x + wd.y*xB.y + wd.z*xB.z + wd.w*xB.w;
        const int b = b0 + k;
        uhat[((size_t)(b * D_ + d) * P_ + p) * 8 + tl] = pack_bf16(u0, u1);

        // s0 partial: sum u over the wave's 8 teams (exact f32, pre-quantization)
        float sa0 = u0, sa1 = u1;
        sa0 += __shfl_xor(sa0, 8);  sa1 += __shfl_xor(sa1, 8);
        sa0 += __shfl_xor(sa0, 16); sa1 += __shfl_xor(sa1, 16);
        sa0 += __shfl_xor(sa0, 32); sa1 += __shfl_xor(sa1, 32);
        if (lane < 8) { sred[kb][wave][2 * lane] = sa0; sred[kb][wave][2 * lane + 1] = sa1; }
        __syncthreads();
        if (tid < 8) {
            float v0 = 0.f, v1 = 0.f;
            #pragma unroll
            for (int w = 0; w < 6; ++w) { v0 += sred[kb][w][2 * tid]; v1 += sred[kb][w][2 * tid + 1]; }
            float2 o; o.x = v0; o.y = v1;
            *(float2*)&s_part[(((size_t)pt * B_ + b) * D_ + d) * I_ + 2 * tid] = o;
        }
    }
}

// Sum the 24 p-tile partials -> s (x0.1), accumulate n2 = sum s^2.
__global__ __launch_bounds__(256) void k_sred(const float* __restrict__ s_part,
                                              float* __restrict__ s, float* __restrict__ n2)
{
    const int gid = blockIdx.x * 256 + threadIdx.x;   // 0..40959 = (b,d,i)
    float v = 0.f;
    #pragma unroll
    for (int pt = 0; pt < NPT; ++pt) v += s_part[(size_t)pt * (B_ * D_ * I_) + gid];
    v *= 0.1f;
    s[gid] = v;
    float v2 = v * v;
    #pragma unroll
    for (int st = 1; st < 64; st <<= 1) v2 += __shfl_xor(v2, st);
    __shared__ float r4[4];
    const int lane = threadIdx.x & 63, wave = threadIdx.x >> 6;
    if (lane == 0) r4[wave] = v2;
    __syncthreads();
    if (threadIdx.x == 0) atomicAdd(n2, r4[0] + r4[1] + r4[2] + r4[3]);
}

// Block per b. Reads u_hat once; logits beta = u_hat . t (t = sum_r g_r*s_r),
// softmax over d, accumulates s_r, n2 partial.
__global__ __launch_bounds__(1024) void k_route(
    const uint32_t* __restrict__ uhat, const float* __restrict__ t,
    float* __restrict__ s, float* __restrict__ n2)
{
    const int b = blockIdx.x;
    const int tid = threadIdx.x;

    __shared__ float tls[D_ * I_];
    __shared__ float sw[16][D_ * I_];
    __shared__ float n2l;

    if (tid < D_ * I_) tls[tid] = t[(size_t)b * D_ * I_ + tid];
    if (tid == 0) n2l = 0.f;
    __syncthreads();

    const int team = tid >> 3;   // 0..127
    const int tl = tid & 7;      // i-pair (2tl, 2tl+1)
    float sacc[D_][2];
    #pragma unroll
    for (int d = 0; d < D_; ++d) { sacc[d][0] = 0.f; sacc[d][1] = 0.f; }

    for (int k = 0; k < 9; ++k) {
        const int p = team + k * 128;
        const uint32_t* up = uhat + ((size_t)b * D_ * P_ + p) * 8 + tl;
        float u[D_][2];
        float beta[D_];
        #pragma unroll
        for (int d = 0; d < D_; ++d) {
            const uint32_t w = up[(size_t)d * P_ * 8];
            const float u0 = __uint_as_float(w << 16);
            const float u1 = __uint_as_float(w & 0xffff0000u);
            u[d][0] = u0; u[d][1] = u1;
            float bp = u0 * tls[d * I_ + 2 * tl] + u1 * tls[d * I_ + 2 * tl + 1];
            bp += __shfl_xor(bp, 1);
            bp += __shfl_xor(bp, 2);
            bp += __shfl_xor(bp, 4);
            beta[d] = bp;
        }
        float m = beta[0];
        #pragma unroll
        for (int d = 1; d < D_; ++d) m = fmaxf(m, beta[d]);
        float c[D_]; float Z = 0.f;
        #pragma unroll
        for (int d = 0; d < D_; ++d) { c[d] = __expf(beta[d] - m); Z += c[d]; }
        const float rz = 1.f / Z;
        #pragma unroll
        for (int d = 0; d < D_; ++d) {
            const float cd = c[d] * rz;
            sacc[d][0] += cd * u[d][0];
            sacc[d][1] += cd * u[d][1];
        }
    }

    // reduce over 8 teams within each wave
    #pragma unroll
    for (int st = 8; st < 64; st <<= 1) {
        #pragma unroll
        for (int d = 0; d < D_; ++d) {
            sacc[d][0] += __shfl_xor(sacc[d][0], st);
            sacc[d][1] += __shfl_xor(sacc[d][1], st);
        }
    }
    const int wave = tid >> 6, lane = tid & 63;
    if (lane < 8) {
        #pragma unroll
        for (int d = 0; d < D_; ++d) {
            sw[wave][d * I_ + 2 * tl]     = sacc[d][0];
            sw[wave][d * I_ + 2 * tl + 1] = sacc[d][1];
        }
    }
    __syncthreads();

    if (tid < D_ * I_) {
        float v = 0.f;
        #pragma unroll
        for (int w2 = 0; w2 < 16; ++w2) v += sw[w2][tid];
        s[(size_t)b * D_ * I_ + tid] = v;
        atomicAdd(&n2l, v * v);
    }
    __syncthreads();
    if (tid == 0) atomicAdd(n2, n2l);
}

// g = (n2/(n2+1))/(sqrt(n2)+eps); mode 0: t = g*s; mode 1: t += g*s; mode 2: out = g*s
__global__ void k_squash(const float* __restrict__ s, float* __restrict__ t,
                         float* __restrict__ out, const float* __restrict__ n2p, int mode)
{
    const int i = blockIdx.x * 256 + threadIdx.x;
    const float n2 = *n2p;
    const float g = (n2 / (n2 + 1.f)) / (sqrtf(n2) + 1e-7f);
    const float v = g * s[i];
    if (mode == 0)      t[i] = v;
    else if (mode == 1) t[i] += v;
    else                out[i] = v;
}

extern "C" void kernel_launch(void* const* d_in, const int* in_sizes, int n_in,
                              void* d_out, int out_size, void* d_ws, size_t ws_size,
                              hipStream_t stream)
{
    const float* x = (const float*)d_in[0];   // [256,1152,8]
    const float* W = (const float*)d_in[1];   // [10,1152,16,8]
    float* out = (float*)d_out;               // [256,10,16]

    char* ws = (char*)d_ws;
    uint32_t* uhat = (uint32_t*)ws;                              // bf16x2, 94,371,840 B
    const size_t uhat_bytes = (size_t)B_ * D_ * P_ * I_ * 2;
    float* s_part = (float*)(ws + uhat_bytes);                   // [24][B,D,16] = 3.93 MB
    float* s  = s_part + (size_t)NPT * B_ * D_ * I_;             // [B,D,16]
    float* t  = s + B_ * D_ * I_;                                // [B,D,16]
    float* n2 = t + B_ * D_ * I_;                                // [3]

    hipMemsetAsync(n2, 0, 3 * sizeof(float), stream);

    // r = 0: u_hat production + uniform-c partial sums (c = 0.1)
    k_uhat<<<8 * (NPT / 8) * D_ * NBC, 384, 0, stream>>>(x, W, uhat, s_part);
    k_sred<<<(B_ * D_ * I_) / 256, 256, 0, stream>>>(s_part, s, n2 + 0);
    k_squash<<<(B_ * D_ * I_) / 256, 256, 0, stream>>>(s, t, out, n2 + 0, 0);
    // r = 1
    k_route<<<B_, 1024, 0, stream>>>(uhat, t, s, n2 + 1);
    k_squash<<<(B_ * D_ * I_) / 256, 256, 0, stream>>>(s, t, out, n2 + 1, 1);
    // r = 2
    k_route<<<B_, 1024, 0, stream>>>(uhat, t, s, n2 + 2);
    k_squash<<<(B_ * D_ * I_) / 256, 256, 0, stream>>>(s, t, out, n2 + 2, 2);
}

// Round 3
// 100.693 us; speedup vs baseline: 1.5473x; 1.1711x over previous
//
#include <hip/hip_runtime.h>
#include <hip/hip_bf16.h>
#include <stdint.h>

#define B_ 256
#define D_ 10
#define P_ 1152
#define I_ 16
#define J_ 8

#define PG 48        // p per k_uhat block
#define NPT 24       // p-groups = partial slices

__device__ inline uint32_t pack_bf16(float a, float b) {
    uint32_t ua = __float_as_uint(a);
    uint32_t ub = __float_as_uint(b);
    // round-to-nearest-even bf16 truncation
    ua = (ua + 0x7fffu + ((ua >> 16) & 1u)) >> 16;
    ub = (ub + 0x7fffu + ((ub >> 16) & 1u)) >> 16;
    return ua | (ub << 16);
}

// Block = (p-group of 48, d, b-half of 128). Lane owns (b, i-half) and loops
// over p: s0-partials accumulate IN REGISTERS (no barrier/shfl in the loop).
// W[d, p-group] staged once in LDS; x read from global (L1/L2-hot).
__global__ __launch_bounds__(256) void k_uhat(
    const float* __restrict__ x, const float* __restrict__ W,
    uint32_t* __restrict__ uhat, float* __restrict__ s_part)
{
    const int bid = blockIdx.x;
    const int bh = bid & 1;
    const int pd = bid >> 1;
    const int d = pd % D_;
    const int pg = pd / D_;
    const int p0 = pg * PG;

    const int tid = threadIdx.x;
    const int ih = tid & 1;              // i-half: i = ih*8 .. ih*8+7
    const int b = bh * 128 + (tid >> 1);

    __shared__ float4 Wl[PG * 32];       // [p][i][j4]: 24 KB

    const float4* wg = (const float4*)(W + (size_t)(d * P_ + p0) * 128);
    for (int k = tid; k < PG * 32; k += 256) Wl[k] = wg[k];
    __syncthreads();

    float sacc[8];
    #pragma unroll
    for (int i = 0; i < 8; ++i) sacc[i] = 0.f;

    const float4* xb = (const float4*)(x + ((size_t)b * P_ + p0) * J_);
    uint4* ub = (uint4*)(uhat + ((size_t)(b * D_ + d) * P_ + p0) * 8) + ih;

    float4 xA = xb[0], xB = xb[1];
    for (int pp = 0; pp < PG; ++pp) {
        float4 nA = xA, nB = xB;
        if (pp + 1 < PG) { nA = xb[(pp + 1) * 2]; nB = xb[(pp + 1) * 2 + 1]; }

        const float4* wp = &Wl[pp * 32 + ih * 16];
        float u[8];
        #pragma unroll
        for (int i = 0; i < 8; ++i) {
            const float4 wA = wp[i * 2], wB = wp[i * 2 + 1];
            u[i] = wA.x*xA.x + wA.y*xA.y + wA.z*xA.z + wA.w*xA.w
                 + wB.x*xB.x + wB.y*xB.y + wB.z*xB.z + wB.w*xB.w;
            sacc[i] += u[i];
        }
        uint4 w;
        w.x = pack_bf16(u[0], u[1]); w.y = pack_bf16(u[2], u[3]);
        w.z = pack_bf16(u[4], u[5]); w.w = pack_bf16(u[6], u[7]);
        ub[pp * 2] = w;
        xA = nA; xB = nB;
    }

    float4* sp = (float4*)(s_part + (size_t)pg * (B_ * D_ * I_)
                           + (size_t)b * (D_ * I_) + d * 16 + ih * 8);
    sp[0] = make_float4(sacc[0], sacc[1], sacc[2], sacc[3]);
    sp[1] = make_float4(sacc[4], sacc[5], sacc[6], sacc[7]);
}

// Sum the 24 p-group partials -> s0 (x0.1), accumulate n2_0 = sum s0^2.
__global__ __launch_bounds__(256) void k_sred(const float* __restrict__ s_part,
                                              float* __restrict__ s, float* __restrict__ n2)
{
    const int gid = blockIdx.x * 256 + threadIdx.x;   // (b,d,i)
    float v = 0.f;
    #pragma unroll
    for (int pt = 0; pt < NPT; ++pt) v += s_part[(size_t)pt * (B_ * D_ * I_) + gid];
    v *= 0.1f;
    s[gid] = v;
    float v2 = v * v;
    #pragma unroll
    for (int st = 1; st < 64; st <<= 1) v2 += __shfl_xor(v2, st);
    __shared__ float r4[4];
    const int lane = threadIdx.x & 63, wave = threadIdx.x >> 6;
    if (lane == 0) r4[wave] = v2;
    __syncthreads();
    if (threadIdx.x == 0) atomicAdd(n2, r4[0] + r4[1] + r4[2] + r4[3]);
}

// Block per b. tls = g0*s0 (+ g1*s1 if rnd==2) computed in-block from n2
// scalars; logits = u_hat . tls; softmax over d; accumulate s_out, n2[rnd].
__global__ __launch_bounds__(1024) void k_route(
    const uint32_t* __restrict__ uhat,
    const float* __restrict__ s0, const float* __restrict__ s1,
    const float* __restrict__ n2v, int rnd,
    float* __restrict__ s_out)
{
    const int b = blockIdx.x;
    const int tid = threadIdx.x;

    __shared__ float tls[D_ * I_];
    __shared__ float sw[16][D_ * I_];
    __shared__ float n2l;

    if (tid < D_ * I_) {
        const float n20 = n2v[0];
        const float g0 = (n20 / (n20 + 1.f)) / (sqrtf(n20) + 1e-7f);
        float v = g0 * s0[(size_t)b * D_ * I_ + tid];
        if (rnd == 2) {
            const float n21 = n2v[1];
            const float g1 = (n21 / (n21 + 1.f)) / (sqrtf(n21) + 1e-7f);
            v += g1 * s1[(size_t)b * D_ * I_ + tid];
        }
        tls[tid] = v;
    }
    if (tid == 0) n2l = 0.f;
    __syncthreads();

    const int team = tid >> 3;   // 0..127
    const int tl = tid & 7;      // i-pair (2tl, 2tl+1)
    float sacc[D_][2];
    #pragma unroll
    for (int d = 0; d < D_; ++d) { sacc[d][0] = 0.f; sacc[d][1] = 0.f; }

    for (int k = 0; k < 9; ++k) {
        const int p = team + k * 128;
        const uint32_t* up = uhat + ((size_t)b * D_ * P_ + p) * 8 + tl;
        float u[D_][2];
        float beta[D_];
        #pragma unroll
        for (int d = 0; d < D_; ++d) {
            const uint32_t w = up[(size_t)d * P_ * 8];
            const float u0 = __uint_as_float(w << 16);
            const float u1 = __uint_as_float(w & 0xffff0000u);
            u[d][0] = u0; u[d][1] = u1;
            float bp = u0 * tls[d * I_ + 2 * tl] + u1 * tls[d * I_ + 2 * tl + 1];
            bp += __shfl_xor(bp, 1);
            bp += __shfl_xor(bp, 2);
            bp += __shfl_xor(bp, 4);
            beta[d] = bp;
        }
        float m = beta[0];
        #pragma unroll
        for (int d = 1; d < D_; ++d) m = fmaxf(m, beta[d]);
        float c[D_]; float Z = 0.f;
        #pragma unroll
        for (int d = 0; d < D_; ++d) { c[d] = __expf(beta[d] - m); Z += c[d]; }
        const float rz = 1.f / Z;
        #pragma unroll
        for (int d = 0; d < D_; ++d) {
            const float cd = c[d] * rz;
            sacc[d][0] += cd * u[d][0];
            sacc[d][1] += cd * u[d][1];
        }
    }

    #pragma unroll
    for (int st = 8; st < 64; st <<= 1) {
        #pragma unroll
        for (int d = 0; d < D_; ++d) {
            sacc[d][0] += __shfl_xor(sacc[d][0], st);
            sacc[d][1] += __shfl_xor(sacc[d][1], st);
        }
    }
    const int wave = tid >> 6, lane = tid & 63;
    if (lane < 8) {
        #pragma unroll
        for (int d = 0; d < D_; ++d) {
            sw[wave][d * I_ + 2 * tl]     = sacc[d][0];
            sw[wave][d * I_ + 2 * tl + 1] = sacc[d][1];
        }
    }
    __syncthreads();

    if (tid < D_ * I_) {
        float v = 0.f;
        #pragma unroll
        for (int w2 = 0; w2 < 16; ++w2) v += sw[w2][tid];
        s_out[(size_t)b * D_ * I_ + tid] = v;
        atomicAdd(&n2l, v * v);
    }
    __syncthreads();
    if (tid == 0) atomicAdd((float*)(n2v + rnd), n2l);
}

// Final in-place rescale: out *= g(n2_2)
__global__ void k_out(float* __restrict__ out, const float* __restrict__ n2p)
{
    const int i = blockIdx.x * 256 + threadIdx.x;
    const float n2 = *n2p;
    const float g = (n2 / (n2 + 1.f)) / (sqrtf(n2) + 1e-7f);
    out[i] *= g;
}

extern "C" void kernel_launch(void* const* d_in, const int* in_sizes, int n_in,
                              void* d_out, int out_size, void* d_ws, size_t ws_size,
                              hipStream_t stream)
{
    const float* x = (const float*)d_in[0];   // [256,1152,8]
    const float* W = (const float*)d_in[1];   // [10,1152,16,8]
    float* out = (float*)d_out;               // [256,10,16]

    char* ws = (char*)d_ws;
    uint32_t* uhat = (uint32_t*)ws;                              // bf16x2, 94,371,840 B
    const size_t uhat_bytes = (size_t)B_ * D_ * P_ * I_ * 2;
    float* s_part = (float*)(ws + uhat_bytes);                   // [24][B*D*I] = 3.93 MB
    float* s0 = s_part + (size_t)NPT * B_ * D_ * I_;             // [B*D*I]
    float* s1 = s0 + B_ * D_ * I_;                               // [B*D*I]
    float* n2 = s1 + B_ * D_ * I_;                               // [3]

    hipMemsetAsync(n2, 0, 3 * sizeof(float), stream);

    // r = 0: u_hat production + uniform-c (0.1) partial sums
    k_uhat<<<NPT * D_ * 2, 256, 0, stream>>>(x, W, uhat, s_part);
    k_sred<<<(B_ * D_ * I_) / 256, 256, 0, stream>>>(s_part, s0, n2 + 0);
    // r = 1: t = g0*s0
    k_route<<<B_, 1024, 0, stream>>>(uhat, s0, s1, n2, 1, s1);
    // r = 2: t = g0*s0 + g1*s1; raw s2 written straight into d_out
    k_route<<<B_, 1024, 0, stream>>>(uhat, s0, s1, n2, 2, out);
    // out = g2 * s2 (in place)
    k_out<<<(B_ * D_ * I_) / 256, 256, 0, stream>>>(out, n2 + 2);
}

// Round 4
// 96.683 us; speedup vs baseline: 1.6115x; 1.0415x over previous
//
#include <hip/hip_runtime.h>
#include <hip/hip_bf16.h>
#include <stdint.h>

#define B_ 256
#define D_ 10
#define P_ 1152
#define I_ 16
#define J_ 8

#define PG 48        // p per k_uhat block
#define NPT 24       // p-groups
#define SLOTS 9216   // u32 slots per (b,d) = P_*8
#define WSP 193      // padded LDS stride (PG*4 + 1 float4s)

__device__ inline uint32_t pack_bf16(float a, float b) {
    uint32_t ua = __float_as_uint(a);
    uint32_t ub = __float_as_uint(b);
    ua = (ua + 0x7fffu + ((ua >> 16) & 1u)) >> 16;
    ub = (ub + 0x7fffu + ((ub >> 16) & 1u)) >> 16;
    return ua | (ub << 16);
}

// uhat u32 layout per (b,d): slot = pq*32 + c*4 + p4   (p = pq*4+p4, c = i-pair)
// Block = (pg, d, b-chunk of 32); lane = (b, c); s0 accumulates in registers.
// Wave stores = 8 x 128B full lines. W in LDS [c][p][q] padded -> conflict-free.
// bid&7 = XCD: each XCD owns pg in {g, g+8, g+16} for all (d, bc).
__global__ __launch_bounds__(256) void k_uhat(
    const float* __restrict__ x, const float* __restrict__ W,
    uint32_t* __restrict__ uhat, float* __restrict__ s_part)
{
    const int bid = blockIdx.x;
    const int g = bid & 7;
    const int fam = bid >> 3;            // 0..239
    const int pg = g + 8 * (fam % 3);
    const int rem = fam / 3;             // 0..79
    const int d = rem % D_;
    const int bc = rem / D_;             // 0..7

    const int p0 = pg * PG;
    const int tid = threadIdx.x;
    const int c = tid & 7;               // i-pair: i = 2c, 2c+1
    const int b = bc * 32 + (tid >> 3);

    __shared__ float4 Wl[8 * WSP];       // 24,704 B

    // stage W[d, p0..p0+47] ; global-contiguous reads, one-time scattered LDS writes
    const float4* wg = (const float4*)(W + (size_t)(d * P_ + p0) * 128);
    for (int k = tid; k < PG * 32; k += 256) {
        const int pl = k >> 5;
        const int cc = (k >> 2) & 7;
        const int q = k & 3;
        Wl[cc * WSP + pl * 4 + q] = wg[k];
    }
    __syncthreads();

    float sacc0 = 0.f, sacc1 = 0.f;
    const float4* xb = (const float4*)(x + ((size_t)b * P_ + p0) * J_);
    uint4* ub = (uint4*)uhat + ((size_t)(b * D_ + d) * SLOTS >> 2) + c;
    const int pqg0 = pg * 12;            // global pq base

    for (int pql = 0; pql < 12; ++pql) {
        float4 xv[4][2];
        #pragma unroll
        for (int p4 = 0; p4 < 4; ++p4) {
            xv[p4][0] = xb[(pql * 4 + p4) * 2];
            xv[p4][1] = xb[(pql * 4 + p4) * 2 + 1];
        }
        uint32_t wr[4];
        #pragma unroll
        for (int p4 = 0; p4 < 4; ++p4) {
            const float4* wp = &Wl[c * WSP + (pql * 4 + p4) * 4];
            const float4 wA = wp[0], wB = wp[1], wC = wp[2], wD = wp[3];
            const float4 xA = xv[p4][0], xB = xv[p4][1];
            float u0 = wA.x*xA.x + wA.y*xA.y + wA.z*xA.z + wA.w*xA.w
                     + wB.x*xB.x + wB.y*xB.y + wB.z*xB.z + wB.w*xB.w;
            float u1 = wC.x*xA.x + wC.y*xA.y + wC.z*xA.z + wC.w*xA.w
                     + wD.x*xB.x + wD.y*xB.y + wD.z*xB.z + wD.w*xB.w;
            sacc0 += u0; sacc1 += u1;
            wr[p4] = pack_bf16(u0, u1);
        }
        uint4 w4; w4.x = wr[0]; w4.y = wr[1]; w4.z = wr[2]; w4.w = wr[3];
        ub[(size_t)(pqg0 + pql) * 8] = w4;
    }

    float2 o; o.x = sacc0; o.y = sacc1;
    *(float2*)&s_part[(((size_t)pg * B_ + b) * D_ + d) * I_ + 2 * c] = o;
}

// Sum the 24 p-group partials -> s0 (x0.1), n2_0 = sum s0^2.
__global__ __launch_bounds__(256) void k_sred(const float* __restrict__ s_part,
                                              float* __restrict__ s, float* __restrict__ n2)
{
    const int gid = blockIdx.x * 256 + threadIdx.x;   // (b,d,i)
    float v = 0.f;
    #pragma unroll
    for (int pt = 0; pt < NPT; ++pt) v += s_part[(size_t)pt * (B_ * D_ * I_) + gid];
    v *= 0.1f;
    s[gid] = v;
    float v2 = v * v;
    #pragma unroll
    for (int st = 1; st < 64; st <<= 1) v2 += __shfl_xor(v2, st);
    __shared__ float r4[4];
    const int lane = threadIdx.x & 63, wave = threadIdx.x >> 6;
    if (lane == 0) r4[wave] = v2;
    __syncthreads();
    if (threadIdx.x == 0) atomicAdd(n2, r4[0] + r4[1] + r4[2] + r4[3]);
}

// Block per b. tls = g0*s0 (+ g1*s1 if rnd==2); logits = u_hat . tls;
// softmax over d; accumulate s_out, n2[rnd]. Wave reads 256B contiguous.
__global__ __launch_bounds__(1024) void k_route(
    const uint32_t* __restrict__ uhat,
    const float* __restrict__ s0, const float* __restrict__ s1,
    const float* __restrict__ n2v, int rnd,
    float* __restrict__ s_out)
{
    const int b = blockIdx.x;
    const int tid = threadIdx.x;

    __shared__ float tls[D_ * I_];
    __shared__ float sw[16][D_ * I_];
    __shared__ float n2l;

    if (tid < D_ * I_) {
        const float n20 = n2v[0];
        const float g0 = (n20 / (n20 + 1.f)) / (sqrtf(n20) + 1e-7f);
        float v = g0 * s0[(size_t)b * D_ * I_ + tid];
        if (rnd == 2) {
            const float n21 = n2v[1];
            const float g1 = (n21 / (n21 + 1.f)) / (sqrtf(n21) + 1e-7f);
            v += g1 * s1[(size_t)b * D_ * I_ + tid];
        }
        tls[tid] = v;
    }
    if (tid == 0) n2l = 0.f;
    __syncthreads();

    const int wv = tid >> 6;     // wave 0..15
    const int l = tid & 63;
    const int tb = l >> 3;       // team-in-wave 0..7
    const int tl = l & 7;        // i-pair
    const uint32_t* ubase = uhat + (size_t)b * D_ * SLOTS;

    float sacc[D_][2];
    #pragma unroll
    for (int d = 0; d < D_; ++d) { sacc[d][0] = 0.f; sacc[d][1] = 0.f; }

    for (int k = 0; k < 9; ++k) {
        const int pqb = k * 32 + wv * 2;
        const int slot = (pqb + (tb >> 2)) * 32 + tl * 4 + (tb & 3);
        const uint32_t* up = ubase + slot;
        float u[D_][2];
        float beta[D_];
        #pragma unroll
        for (int d = 0; d < D_; ++d) {
            const uint32_t w = up[(size_t)d * SLOTS];
            const float u0 = __uint_as_float(w << 16);
            const float u1 = __uint_as_float(w & 0xffff0000u);
            u[d][0] = u0; u[d][1] = u1;
            float bp = u0 * tls[d * I_ + 2 * tl] + u1 * tls[d * I_ + 2 * tl + 1];
            bp += __shfl_xor(bp, 1);
            bp += __shfl_xor(bp, 2);
            bp += __shfl_xor(bp, 4);
            beta[d] = bp;
        }
        float m = beta[0];
        #pragma unroll
        for (int d = 1; d < D_; ++d) m = fmaxf(m, beta[d]);
        float cc[D_]; float Z = 0.f;
        #pragma unroll
        for (int d = 0; d < D_; ++d) { cc[d] = __expf(beta[d] - m); Z += cc[d]; }
        const float rz = 1.f / Z;
        #pragma unroll
        for (int d = 0; d < D_; ++d) {
            const float cd = cc[d] * rz;
            sacc[d][0] += cd * u[d][0];
            sacc[d][1] += cd * u[d][1];
        }
    }

    #pragma unroll
    for (int st = 8; st < 64; st <<= 1) {
        #pragma unroll
        for (int d = 0; d < D_; ++d) {
            sacc[d][0] += __shfl_xor(sacc[d][0], st);
            sacc[d][1] += __shfl_xor(sacc[d][1], st);
        }
    }
    if (l < 8) {
        #pragma unroll
        for (int d = 0; d < D_; ++d) {
            sw[wv][d * I_ + 2 * tl]     = sacc[d][0];
            sw[wv][d * I_ + 2 * tl + 1] = sacc[d][1];
        }
    }
    __syncthreads();

    if (tid < D_ * I_) {
        float v = 0.f;
        #pragma unroll
        for (int w2 = 0; w2 < 16; ++w2) v += sw[w2][tid];
        s_out[(size_t)b * D_ * I_ + tid] = v;
        atomicAdd(&n2l, v * v);
    }
    __syncthreads();
    if (tid == 0) atomicAdd((float*)(n2v + rnd), n2l);
}

// Final in-place rescale: out *= g(n2_2)
__global__ void k_out(float* __restrict__ out, const float* __restrict__ n2p)
{
    const int i = blockIdx.x * 256 + threadIdx.x;
    const float n2 = *n2p;
    const float g = (n2 / (n2 + 1.f)) / (sqrtf(n2) + 1e-7f);
    out[i] *= g;
}

extern "C" void kernel_launch(void* const* d_in, const int* in_sizes, int n_in,
                              void* d_out, int out_size, void* d_ws, size_t ws_size,
                              hipStream_t stream)
{
    const float* x = (const float*)d_in[0];   // [256,1152,8]
    const float* W = (const float*)d_in[1];   // [10,1152,16,8]
    float* out = (float*)d_out;               // [256,10,16]

    char* ws = (char*)d_ws;
    uint32_t* uhat = (uint32_t*)ws;                              // bf16x2, 94,371,840 B
    const size_t uhat_bytes = (size_t)B_ * D_ * P_ * I_ * 2;
    float* s_part = (float*)(ws + uhat_bytes);                   // [24][B*D*I] = 3.93 MB
    float* s0 = s_part + (size_t)NPT * B_ * D_ * I_;             // [B*D*I]
    float* s1 = s0 + B_ * D_ * I_;                               // [B*D*I]
    float* n2 = s1 + B_ * D_ * I_;                               // [3]

    hipMemsetAsync(n2, 0, 3 * sizeof(float), stream);

    // r = 0: u_hat production + uniform-c (0.1) partial sums
    k_uhat<<<NPT * D_ * 8, 256, 0, stream>>>(x, W, uhat, s_part);
    k_sred<<<(B_ * D_ * I_) / 256, 256, 0, stream>>>(s_part, s0, n2 + 0);
    // r = 1: t = g0*s0
    k_route<<<B_, 1024, 0, stream>>>(uhat, s0, s1, n2, 1, s1);
    // r = 2: t = g0*s0 + g1*s1; raw s2 -> d_out
    k_route<<<B_, 1024, 0, stream>>>(uhat, s0, s1, n2, 2, out);
    // out = g2 * s2 (in place)
    k_out<<<(B_ * D_ * I_) / 256, 256, 0, stream>>>(out, n2 + 2);
}